// Round 3
// baseline (354.514 us; speedup 1.0000x reference)
//
#include <hip/hip_runtime.h>

// Varlen depthwise conv (Canon layer): out = x + bias + sum_k mask*w[:,k]*x[t+k-2]
// T=65536 tokens, C=768 channels, K=5, NSEQ=16 packed sequences.
// Memory-bound: ~402 MB min traffic. Timed harness graph also contains ~249 us
// of fixed poison-fill cost; the kernel itself is the only optimizable part.
//
// This version: per-block uniform fast path (no masks / no per-token seq scan
// for the >99% of blocks that contain no sequence boundary), TPB=32 (halo
// over-fetch 25% -> 12.5%), vectorized weight loads, non-temporal stores
// (output is write-once; keep L2/L3 for the input stream's halo reuse).
// NT store goes through a native clang ext_vector_type: the builtin rejects
// HIP_vector_type<float,4> (round-2 compile error).

#define CC  768          // channels
#define C4V (CC / 4)     // float4 chunks per row = 192 (block size, 3 waves)
#define KK  5            // kernel taps
#define RR  2            // radius
#define TPB 32           // tokens per block (sliding-window reuse)

typedef float nfloat4 __attribute__((ext_vector_type(4)));

__device__ __forceinline__ void nt_store(float4* p, const float4& v) {
    __builtin_nontemporal_store(*reinterpret_cast<const nfloat4*>(&v),
                                reinterpret_cast<nfloat4*>(p));
}

// wl[] holds 20 consecutive floats weight[c*K .. c*K+19] = taps for 4 channels.
// W(k, j) = weight[(c+j)*K + k]
#define W(k, j) wl[(j) * KK + (k)]

__global__ __launch_bounds__(C4V, 4) void canon_dwconv_kernel(
    const float4* __restrict__ x4,
    const int*    __restrict__ cu,    // cu_seqlens, nseq+1 entries, cu[nseq]=T
    int nseq,
    const float4* __restrict__ w4,    // weight [C,K] row-major, viewed as float4
    const float4* __restrict__ bias4, // [C/4]
    float4*       __restrict__ out4,
    int T)
{
    const int c4 = threadIdx.x;
    const int t0 = (int)blockIdx.x * TPB;

    // Per-thread tap weights for 4 channels: 20 consecutive floats -> 5 float4s
    float wl[KK * 4];
#pragma unroll
    for (int i = 0; i < KK; ++i) {
        const float4 v = w4[c4 * KK + i];
        wl[4 * i + 0] = v.x; wl[4 * i + 1] = v.y;
        wl[4 * i + 2] = v.z; wl[4 * i + 3] = v.w;
    }
    const float4 b = bias4[c4];

    // Per-block (wave-uniform) sequence lookup: sid s.t. cu[sid] <= t0 < cu[sid+1]
    int sid = 0;
    while (sid < nseq && cu[sid + 1] <= t0) ++sid;
    const int s0 = cu[sid];
    const int e0 = cu[sid + 1];

    const float4* __restrict__ xrow = x4 + c4;
    float4*       __restrict__ orow = out4 + c4;

    if (s0 <= t0 - RR && e0 >= t0 + TPB + RR) {
        // ---------- FAST PATH: whole block + halo inside one sequence ----------
        // All masks are 1, no clamping needed (s0 >= 0, e0 <= T bound the halo).
        float4 win[KK];
#pragma unroll
        for (int i = 0; i < KK - 1; ++i)
            win[i] = xrow[(size_t)(t0 - RR + i) * C4V];

#pragma unroll
        for (int tt = 0; tt < TPB; ++tt) {
            const int t = t0 + tt;
            win[(tt + KK - 1) % KK] = xrow[(size_t)(t + RR) * C4V];

            const float4 r0 = win[(tt + 0) % KK];
            const float4 r1 = win[(tt + 1) % KK];
            const float4 r2 = win[(tt + 2) % KK];
            const float4 r3 = win[(tt + 3) % KK];
            const float4 r4 = win[(tt + 4) % KK];

            float4 o;
            o.x = r2.x + b.x + r2.x * W(2,0)
                + r0.x * W(0,0) + r1.x * W(1,0)
                + r3.x * W(3,0) + r4.x * W(4,0);
            o.y = r2.y + b.y + r2.y * W(2,1)
                + r0.y * W(0,1) + r1.y * W(1,1)
                + r3.y * W(3,1) + r4.y * W(4,1);
            o.z = r2.z + b.z + r2.z * W(2,2)
                + r0.z * W(0,2) + r1.z * W(1,2)
                + r3.z * W(3,2) + r4.z * W(4,2);
            o.w = r2.w + b.w + r2.w * W(2,3)
                + r0.w * W(0,3) + r1.w * W(1,3)
                + r3.w * W(3,3) + r4.w * W(4,3);

            nt_store(&orow[(size_t)t * C4V], o);
        }
    } else {
        // ---------- SLOW PATH: boundary / array-edge blocks (~20 of 2048) ----------
        float4 win[KK];
#pragma unroll
        for (int i = 0; i < KK - 1; ++i) {
            int r  = t0 - RR + i;
            int rc = min(max(r, 0), T - 1);
            win[i] = xrow[(size_t)rc * C4V];
        }

#pragma unroll
        for (int tt = 0; tt < TPB; ++tt) {
            const int t = t0 + tt;
            if (t < T) {
                int rc = min(t + RR, T - 1);
                win[(tt + KK - 1) % KK] = xrow[(size_t)rc * C4V];

                while (sid < nseq && cu[sid + 1] <= t) ++sid;
                const int start = cu[sid];
                const int end   = cu[sid + 1];

                const float4 r0 = win[(tt + 0) % KK];
                const float4 r1 = win[(tt + 1) % KK];
                const float4 r2 = win[(tt + 2) % KK];
                const float4 r3 = win[(tt + 3) % KK];
                const float4 r4 = win[(tt + 4) % KK];

                const float m0 = (t - 2 >= start) ? 1.0f : 0.0f;
                const float m1 = (t - 1 >= start) ? 1.0f : 0.0f;
                const float m3 = (t + 1 <  end)  ? 1.0f : 0.0f;
                const float m4 = (t + 2 <  end)  ? 1.0f : 0.0f;

                float4 o;
                o.x = r2.x + b.x + r2.x * W(2,0)
                    + r0.x * (W(0,0) * m0) + r1.x * (W(1,0) * m1)
                    + r3.x * (W(3,0) * m3) + r4.x * (W(4,0) * m4);
                o.y = r2.y + b.y + r2.y * W(2,1)
                    + r0.y * (W(0,1) * m0) + r1.y * (W(1,1) * m1)
                    + r3.y * (W(3,1) * m3) + r4.y * (W(4,1) * m4);
                o.z = r2.z + b.z + r2.z * W(2,2)
                    + r0.z * (W(0,2) * m0) + r1.z * (W(1,2) * m1)
                    + r3.z * (W(3,2) * m3) + r4.z * (W(4,2) * m4);
                o.w = r2.w + b.w + r2.w * W(2,3)
                    + r0.w * (W(0,3) * m0) + r1.w * (W(1,3) * m1)
                    + r3.w * (W(3,3) * m3) + r4.w * (W(4,3) * m4);

                nt_store(&orow[(size_t)t * C4V], o);
            }
        }
    }
}

extern "C" void kernel_launch(void* const* d_in, const int* in_sizes, int n_in,
                              void* d_out, int out_size, void* d_ws, size_t ws_size,
                              hipStream_t stream) {
    const float4* x4     = (const float4*)d_in[0];
    const int*    cu     = (const int*)d_in[1];
    const float4* w4     = (const float4*)d_in[2];
    const float4* bias4  = (const float4*)d_in[3];
    float4*       out4   = (float4*)d_out;

    const int T    = in_sizes[0] / CC;
    const int nseq = in_sizes[1] - 1;

    const int grid = (T + TPB - 1) / TPB;
    canon_dwconv_kernel<<<grid, C4V, 0, stream>>>(x4, cu, nseq, w4, bias4, out4, T);
}

// Round 4
// 335.204 us; speedup vs baseline: 1.0576x; 1.0576x over previous
//
#include <hip/hip_runtime.h>

// Varlen depthwise conv (Canon layer): out = x + bias + sum_k mask*w[:,k]*x[t+k-2]
// T=65536 tokens, C=768 channels, K=5, NSEQ=16 packed sequences.
//
// Round-3 counters: kernel 139 us, HBM 28%, VALUBusy 4%, VGPR=36 -> latency-bound.
// The sliding-window form serialized every token on {load -> use} AND, via
// in-order vmcnt retirement, on the PREVIOUS token's store (made worse by NT
// stores acking at HBM). This version batches: all 12 row-loads issued
// back-to-back (12 outstanding per thread), THEN compute+store. No load is
// ever issued after a store within a block. TPB=8 -> 8192 blocks (3x wave
// oversubscription for cross-wave MLP). Regular stores (L2-ack).

#define CC    768          // channels
#define C4V   (CC / 4)     // float4 chunks per row = 192 (block size, 3 waves)
#define KK    5            // kernel taps
#define RR    2            // radius
#define TPB   8            // tokens per block
#define NROWS (TPB + 2 * RR)  // 12 rows incl. halo

// wl[] holds 20 consecutive floats weight[c*K .. c*K+19] = taps for 4 channels.
// W(k, j) = weight[(c+j)*K + k]
#define W(k, j) wl[(j) * KK + (k)]

__global__ __launch_bounds__(C4V) void canon_dwconv_kernel(
    const float4* __restrict__ x4,
    const int*    __restrict__ cu,    // cu_seqlens, nseq+1 entries, cu[nseq]=T
    int nseq,
    const float4* __restrict__ w4,    // weight [C,K] row-major, viewed as float4
    const float4* __restrict__ bias4, // [C/4]
    float4*       __restrict__ out4,
    int T)
{
    const int c4 = threadIdx.x;
    const int t0 = (int)blockIdx.x * TPB;

    // Per-thread tap weights for 4 channels: 20 consecutive floats -> 5 float4s
    float wl[KK * 4];
#pragma unroll
    for (int i = 0; i < KK; ++i) {
        const float4 v = w4[c4 * KK + i];
        wl[4 * i + 0] = v.x; wl[4 * i + 1] = v.y;
        wl[4 * i + 2] = v.z; wl[4 * i + 3] = v.w;
    }
    const float4 b = bias4[c4];

    // Per-block (wave-uniform) sequence lookup: sid s.t. cu[sid] <= t0 < cu[sid+1]
    int sid = 0;
    while (sid < nseq && cu[sid + 1] <= t0) ++sid;
    const int s0 = cu[sid];
    const int e0 = cu[sid + 1];

    const float4* __restrict__ xrow = x4 + c4;
    float4*       __restrict__ orow = out4 + c4;

    if (s0 <= t0 - RR && e0 >= t0 + TPB + RR) {
        // ---------- FAST PATH: whole block + halo inside one sequence ----------
        // Rows t0-2 .. t0+TPB+1 all lie in [s0, e0) subset [0, T): no clamps,
        // all masks are 1. Issue all 12 loads before any dependent use/store.
        float4 win[NROWS];
#pragma unroll
        for (int i = 0; i < NROWS; ++i)
            win[i] = xrow[(size_t)(t0 - RR + i) * C4V];

#pragma unroll
        for (int tt = 0; tt < TPB; ++tt) {
            const float4 r0 = win[tt + 0];
            const float4 r1 = win[tt + 1];
            const float4 r2 = win[tt + 2];
            const float4 r3 = win[tt + 3];
            const float4 r4 = win[tt + 4];

            float4 o;
            o.x = r2.x + b.x + r2.x * W(2,0)
                + r0.x * W(0,0) + r1.x * W(1,0)
                + r3.x * W(3,0) + r4.x * W(4,0);
            o.y = r2.y + b.y + r2.y * W(2,1)
                + r0.y * W(0,1) + r1.y * W(1,1)
                + r3.y * W(3,1) + r4.y * W(4,1);
            o.z = r2.z + b.z + r2.z * W(2,2)
                + r0.z * W(0,2) + r1.z * W(1,2)
                + r3.z * W(3,2) + r4.z * W(4,2);
            o.w = r2.w + b.w + r2.w * W(2,3)
                + r0.w * W(0,3) + r1.w * W(1,3)
                + r3.w * W(3,3) + r4.w * W(4,3);

            orow[(size_t)(t0 + tt) * C4V] = o;
        }
    } else {
        // ---------- SLOW PATH: boundary / array-edge blocks (~20 of 8192) ----------
        // Same batch structure; row indices clamped (masks make clamps safe).
        float4 win[NROWS];
#pragma unroll
        for (int i = 0; i < NROWS; ++i) {
            int r  = t0 - RR + i;
            int rc = min(max(r, 0), T - 1);
            win[i] = xrow[(size_t)rc * C4V];
        }

#pragma unroll
        for (int tt = 0; tt < TPB; ++tt) {
            const int t = t0 + tt;
            if (t < T) {
                while (sid < nseq && cu[sid + 1] <= t) ++sid;
                const int start = cu[sid];
                const int end   = cu[sid + 1];

                const float4 r0 = win[tt + 0];
                const float4 r1 = win[tt + 1];
                const float4 r2 = win[tt + 2];
                const float4 r3 = win[tt + 3];
                const float4 r4 = win[tt + 4];

                const float m0 = (t - 2 >= start) ? 1.0f : 0.0f;
                const float m1 = (t - 1 >= start) ? 1.0f : 0.0f;
                const float m3 = (t + 1 <  end)  ? 1.0f : 0.0f;
                const float m4 = (t + 2 <  end)  ? 1.0f : 0.0f;

                float4 o;
                o.x = r2.x + b.x + r2.x * W(2,0)
                    + r0.x * (W(0,0) * m0) + r1.x * (W(1,0) * m1)
                    + r3.x * (W(3,0) * m3) + r4.x * (W(4,0) * m4);
                o.y = r2.y + b.y + r2.y * W(2,1)
                    + r0.y * (W(0,1) * m0) + r1.y * (W(1,1) * m1)
                    + r3.y * (W(3,1) * m3) + r4.y * (W(4,1) * m4);
                o.z = r2.z + b.z + r2.z * W(2,2)
                    + r0.z * (W(0,2) * m0) + r1.z * (W(1,2) * m1)
                    + r3.z * (W(3,2) * m3) + r4.z * (W(4,2) * m4);
                o.w = r2.w + b.w + r2.w * W(2,3)
                    + r0.w * (W(0,3) * m0) + r1.w * (W(1,3) * m1)
                    + r3.w * (W(3,3) * m3) + r4.w * (W(4,3) * m4);

                orow[(size_t)t * C4V] = o;
            }
        }
    }
}

extern "C" void kernel_launch(void* const* d_in, const int* in_sizes, int n_in,
                              void* d_out, int out_size, void* d_ws, size_t ws_size,
                              hipStream_t stream) {
    const float4* x4     = (const float4*)d_in[0];
    const int*    cu     = (const int*)d_in[1];
    const float4* w4     = (const float4*)d_in[2];
    const float4* bias4  = (const float4*)d_in[3];
    float4*       out4   = (float4*)d_out;

    const int T    = in_sizes[0] / CC;
    const int nseq = in_sizes[1] - 1;

    const int grid = (T + TPB - 1) / TPB;
    canon_dwconv_kernel<<<grid, C4V, 0, stream>>>(x4, cu, nseq, w4, bias4, out4, T);
}